// Round 4
// baseline (1535.768 us; speedup 1.0000x reference)
//
#include <hip/hip_runtime.h>

#define LX 6
#define LY 6
#define NSITE 36
#define TSZ (NSITE * 2 * 256)   // transposed, zero-padded site tensors

// T table: Tt[site][s][(v + 4*l)][(v' + 4*r')] ; zero outside valid boundary dims
__device__ float g_Tt[TSZ];

__global__ __launch_bounds__(256) void build_T_kernel(const float* __restrict__ peps) {
    int idx = blockIdx.x * 256 + threadIdx.x;
    if (idx >= TSZ) return;
    int o    = idx & 15;          // v' + 4*r'
    int vl   = (idx >> 4) & 15;   // v + 4*l
    int s    = (idx >> 8) & 1;
    int site = idx >> 9;          // i*LY + j
    int i = site / LY, j = site - i * LY;
    int v = vl & 3, l = vl >> 2, vp = o & 3, rp = o >> 2;
    bool ok = (i > 0 || v == 0) && (i < LX - 1 || vp == 0) &&
              (j > 0 || l == 0) && (j < LY - 1 || rp == 0);
    // peps[i][j][s][u][d][l][r]: strides 512,256,64,16,4,1 (floats)
    g_Tt[idx] = ok ? peps[site * 512 + s * 256 + v * 64 + vp * 16 + l * 4 + rp] : 0.0f;
}

// Bank swizzle: bijection, float4-aligned; XOR bits 5..7 and 8..10 into cluster bits 2..4.
__device__ __forceinline__ int swz(int f) {
    return f ^ ((((f >> 5) ^ (f >> 8)) & 7) << 2);
}

__device__ __forceinline__ void fma4(float4& a, float s, const float4& t) {
    a.x = __builtin_fmaf(s, t.x, a.x);
    a.y = __builtin_fmaf(s, t.y, a.y);
    a.z = __builtin_fmaf(s, t.z, a.z);
    a.w = __builtin_fmaf(s, t.w, a.w);
}

__device__ __forceinline__ float f4c(const float4& v, int i) {
    return i == 0 ? v.x : i == 1 ? v.y : i == 2 ? v.z : v.w;
}

// Fused pair of row-steps (I, I+1) for one column, split across a lane pair.
// env flat (pre-swizzle) = v + 4*s0 + 16*s1 + 64*s2 + 256*s3 + 1024*s4 + 4096*s5.
// rest = tid>>1 owns one rest-combo; apBase = (tid&1)*2 selects this thread's
// half of the a' (slot-I output) range. Lane pair reads the same cube
// (LDS broadcast) and writes disjoint halves; same-wave in-order DS ops make
// the in-place WAR safe without a mid-pair barrier.
// TOPB: site(I,col) has u-dim 1 -> only v=0 input. BOTB: site(I+1,col) has
// d-dim 1 -> only v''=0 output (rest written as exact 0 to keep quarantine).
template<int I, bool TOPB, bool BOTB>
__device__ __forceinline__ void fused_pair(float* env, const float* __restrict__ T1,
                                           const float* __restrict__ T2,
                                           int rest, int apBase) {
    constexpr int S1 = 1 << (2 * I + 2);
    constexpr int S2 = S1 << 2;
    const int lo = rest & ((1 << (2 * I)) - 1);
    const int hi = rest >> (2 * I);
    const int base = 4 * lo + (hi << (2 * I + 6));

    float4 inter[2][4];   // [my a'][b], components = v'
    #pragma unroll
    for (int k = 0; k < 2; ++k)
        #pragma unroll
        for (int bb = 0; bb < 4; ++bb)
            inter[k][bb] = make_float4(0.f, 0.f, 0.f, 0.f);

    // ---- stage 1: inter[v'][a'][b] = sum_{v,a} in[v][a][b] * T1[(v,a),(v',a')] ----
    if (TOPB) {
        #pragma unroll
        for (int a = 0; a < 4; ++a) {
            float in0[4];
            #pragma unroll
            for (int bb = 0; bb < 4; ++bb)
                in0[bb] = env[swz(base + a * S1 + bb * S2)];
            #pragma unroll
            for (int k = 0; k < 2; ++k) {
                float4 t1 = *(const float4*)(T1 + (4 * a) * 16 + 4 * (apBase + k)); // v=0 row
                #pragma unroll
                for (int bb = 0; bb < 4; ++bb)
                    fma4(inter[k][bb], in0[bb], t1);
            }
        }
    } else {
        #pragma unroll
        for (int a = 0; a < 4; ++a) {
            float4 inv[4];
            #pragma unroll
            for (int bb = 0; bb < 4; ++bb)
                inv[bb] = *(const float4*)&env[swz(base + a * S1 + bb * S2)];
            #pragma unroll
            for (int v = 0; v < 4; ++v)
                #pragma unroll
                for (int k = 0; k < 2; ++k) {
                    float4 t1 = *(const float4*)(T1 + (v + 4 * a) * 16 + 4 * (apBase + k));
                    #pragma unroll
                    for (int bb = 0; bb < 4; ++bb)
                        fma4(inter[k][bb], f4c(inv[bb], v), t1);
                }
        }
    }

    // ---- stage 2: out[v''][a'][b'] = sum_{v',b} inter[v'][a'][b] * T2[(v',b),(v'',b')] ----
    #pragma unroll
    for (int k = 0; k < 2; ++k) {
        const int ap = apBase + k;
        if (BOTB) {
            float o[4] = {0.f, 0.f, 0.f, 0.f};
            #pragma unroll
            for (int bb = 0; bb < 4; ++bb)
                #pragma unroll
                for (int vp = 0; vp < 4; ++vp) {
                    float iv = f4c(inter[k][bb], vp);
                    #pragma unroll
                    for (int bp = 0; bp < 4; ++bp)
                        o[bp] = __builtin_fmaf(iv, T2[(vp + 4 * bb) * 16 + 4 * bp], o[bp]);
                }
            #pragma unroll
            for (int bp = 0; bp < 4; ++bp)
                *(float4*)&env[swz(base + ap * S1 + bp * S2)] = make_float4(o[bp], 0.f, 0.f, 0.f);
        } else {
            float4 outv[4];
            #pragma unroll
            for (int bp = 0; bp < 4; ++bp) outv[bp] = make_float4(0.f, 0.f, 0.f, 0.f);
            #pragma unroll
            for (int bb = 0; bb < 4; ++bb)
                #pragma unroll
                for (int vp = 0; vp < 4; ++vp) {
                    float iv = f4c(inter[k][bb], vp);
                    #pragma unroll
                    for (int bp = 0; bp < 4; ++bp) {
                        float4 t2 = *(const float4*)(T2 + (vp + 4 * bb) * 16 + 4 * bp);
                        fma4(outv[bp], iv, t2);
                    }
                }
            #pragma unroll
            for (int bp = 0; bp < 4; ++bp)
                *(float4*)&env[swz(base + ap * S1 + bp * S2)] = outv[bp];
        }
    }
}

__global__ __launch_bounds__(512, 4) void peps_amp_kernel(const int* __restrict__ x,
                                                          float* __restrict__ out) {
    __shared__ float env[16384];
    const int tid = threadIdx.x;
    const int b = blockIdx.x;
    const int* xr = x + b * NSITE;
    const int rest = tid >> 1;
    const int apBase = (tid & 1) * 2;

    // No env zero-init needed: column 0 writes all v=0 slots; column 1's TOPB
    // pair reads exactly those and overwrites the full env; BOTB writes explicit
    // zeros maintaining the v''!=0 quarantine thereafter.

    // ---- column 0: closed-form MPS chain -> env(r0..r5) at flat = 4*(r0+4r1+...+1024r5)
    {
        const float* A0 = g_Tt + ((0 * LY + 0) * 2 + __builtin_amdgcn_readfirstlane(xr[0 * LY])) * 256;
        const float* A1 = g_Tt + ((1 * LY + 0) * 2 + __builtin_amdgcn_readfirstlane(xr[1 * LY])) * 256;
        const float* A2 = g_Tt + ((2 * LY + 0) * 2 + __builtin_amdgcn_readfirstlane(xr[2 * LY])) * 256;
        const float* A3 = g_Tt + ((3 * LY + 0) * 2 + __builtin_amdgcn_readfirstlane(xr[3 * LY])) * 256;
        const float* A4 = g_Tt + ((4 * LY + 0) * 2 + __builtin_amdgcn_readfirstlane(xr[4 * LY])) * 256;
        const float* A5 = g_Tt + ((5 * LY + 0) * 2 + __builtin_amdgcn_readfirstlane(xr[5 * LY])) * 256;
        // A_i(r)[u][d] = T[(u + 4*0)][(d + 4r)]  (l = 0 for column 0)
        const int r2 = rest & 3, r3 = (rest >> 2) & 3, r4 = (rest >> 4) & 3, r5 = (rest >> 6) & 3;
        float w[4], w2[4];
        #pragma unroll
        for (int u = 0; u < 4; ++u) w[u] = A5[u * 16 + 4 * r5];                    // d = 0
        #pragma unroll
        for (int u = 0; u < 4; ++u) { float acc = 0;
            #pragma unroll
            for (int d = 0; d < 4; ++d) acc = __builtin_fmaf(A4[u * 16 + d + 4 * r4], w[d], acc);
            w2[u] = acc; }
        #pragma unroll
        for (int u = 0; u < 4; ++u) { float acc = 0;
            #pragma unroll
            for (int d = 0; d < 4; ++d) acc = __builtin_fmaf(A3[u * 16 + d + 4 * r3], w2[d], acc);
            w[u] = acc; }
        #pragma unroll
        for (int u = 0; u < 4; ++u) { float acc = 0;
            #pragma unroll
            for (int d = 0; d < 4; ++d) acc = __builtin_fmaf(A2[u * 16 + d + 4 * r2], w[d], acc);
            w2[u] = acc; }
        #pragma unroll
        for (int t = 0; t < 2; ++t) {
            const int r1 = apBase + t;     // this thread's half of r1
            float u1[4];
            #pragma unroll
            for (int u = 0; u < 4; ++u) { float acc = 0;
                #pragma unroll
                for (int d = 0; d < 4; ++d) acc = __builtin_fmaf(A1[u * 16 + d + 4 * r1], w2[d], acc);
                u1[u] = acc; }
            #pragma unroll
            for (int r0 = 0; r0 < 4; ++r0) {
                float acc = 0;
                #pragma unroll
                for (int d = 0; d < 4; ++d) acc = __builtin_fmaf(A0[d + 4 * r0], u1[d], acc);
                env[swz(4 * r0 + 16 * r1 + 64 * rest)] = acc;
            }
        }
    }
    __syncthreads();

    // ---- columns 1..4: three fused row-pairs each ----
    #pragma unroll 1
    for (int j = 1; j < LY - 1; ++j) {
        const float* T0 = g_Tt + ((0 * LY + j) * 2 + __builtin_amdgcn_readfirstlane(xr[0 * LY + j])) * 256;
        const float* T1 = g_Tt + ((1 * LY + j) * 2 + __builtin_amdgcn_readfirstlane(xr[1 * LY + j])) * 256;
        const float* T2 = g_Tt + ((2 * LY + j) * 2 + __builtin_amdgcn_readfirstlane(xr[2 * LY + j])) * 256;
        const float* T3 = g_Tt + ((3 * LY + j) * 2 + __builtin_amdgcn_readfirstlane(xr[3 * LY + j])) * 256;
        const float* T4 = g_Tt + ((4 * LY + j) * 2 + __builtin_amdgcn_readfirstlane(xr[4 * LY + j])) * 256;
        const float* T5 = g_Tt + ((5 * LY + j) * 2 + __builtin_amdgcn_readfirstlane(xr[5 * LY + j])) * 256;
        fused_pair<0, true,  false>(env, T0, T1, rest, apBase); __syncthreads();
        fused_pair<2, false, false>(env, T2, T3, rest, apBase); __syncthreads();
        fused_pair<4, false, true >(env, T4, T5, rest, apBase); __syncthreads();
    }

    // ---- column 5: closed-form MPS chain + dot with env ----
    {
        const float* B0 = g_Tt + ((0 * LY + 5) * 2 + __builtin_amdgcn_readfirstlane(xr[0 * LY + 5])) * 256;
        const float* B1 = g_Tt + ((1 * LY + 5) * 2 + __builtin_amdgcn_readfirstlane(xr[1 * LY + 5])) * 256;
        const float* B2 = g_Tt + ((2 * LY + 5) * 2 + __builtin_amdgcn_readfirstlane(xr[2 * LY + 5])) * 256;
        const float* B3 = g_Tt + ((3 * LY + 5) * 2 + __builtin_amdgcn_readfirstlane(xr[3 * LY + 5])) * 256;
        const float* B4 = g_Tt + ((4 * LY + 5) * 2 + __builtin_amdgcn_readfirstlane(xr[4 * LY + 5])) * 256;
        const float* B5 = g_Tt + ((5 * LY + 5) * 2 + __builtin_amdgcn_readfirstlane(xr[5 * LY + 5])) * 256;
        // B_i(l)[u][d] = T[(u + 4l)][(d + 4*0)]  (r' = 0 for column 5)
        const int l2 = rest & 3, l3 = (rest >> 2) & 3, l4 = (rest >> 4) & 3, l5 = (rest >> 6) & 3;
        float w[4], w2[4];
        #pragma unroll
        for (int u = 0; u < 4; ++u) w[u] = B5[(u + 4 * l5) * 16];                  // d = 0
        #pragma unroll
        for (int u = 0; u < 4; ++u) { float acc = 0;
            #pragma unroll
            for (int d = 0; d < 4; ++d) acc = __builtin_fmaf(B4[(u + 4 * l4) * 16 + d], w[d], acc);
            w2[u] = acc; }
        #pragma unroll
        for (int u = 0; u < 4; ++u) { float acc = 0;
            #pragma unroll
            for (int d = 0; d < 4; ++d) acc = __builtin_fmaf(B3[(u + 4 * l3) * 16 + d], w2[d], acc);
            w[u] = acc; }
        #pragma unroll
        for (int u = 0; u < 4; ++u) { float acc = 0;
            #pragma unroll
            for (int d = 0; d < 4; ++d) acc = __builtin_fmaf(B2[(u + 4 * l2) * 16 + d], w[d], acc);
            w2[u] = acc; }
        float partial = 0.f;
        #pragma unroll
        for (int t = 0; t < 2; ++t) {
            const int l1 = apBase + t;     // this thread's half of l1
            float u1[4];
            #pragma unroll
            for (int u = 0; u < 4; ++u) { float acc = 0;
                #pragma unroll
                for (int d = 0; d < 4; ++d) acc = __builtin_fmaf(B1[(u + 4 * l1) * 16 + d], w2[d], acc);
                u1[u] = acc; }
            #pragma unroll
            for (int l0 = 0; l0 < 4; ++l0) {
                float wv = 0.f;
                #pragma unroll
                for (int d = 0; d < 4; ++d) wv = __builtin_fmaf(B0[(4 * l0) * 16 + d], u1[d], wv);
                partial = __builtin_fmaf(env[swz(4 * l0 + 16 * l1 + 64 * rest)], wv, partial);
            }
        }
        #pragma unroll
        for (int off = 32; off; off >>= 1) partial += __shfl_down(partial, off);
        __syncthreads();                       // all env reads done before reuse
        if ((tid & 63) == 0) env[tid >> 6] = partial;
        __syncthreads();
        if (tid == 0)
            out[b] = ((env[0] + env[1]) + (env[2] + env[3]))
                   + ((env[4] + env[5]) + (env[6] + env[7]));
    }
}

extern "C" void kernel_launch(void* const* d_in, const int* in_sizes, int n_in,
                              void* d_out, int out_size, void* d_ws, size_t ws_size,
                              hipStream_t stream) {
    const int* x = (const int*)d_in[0];
    const float* peps = (const float*)d_in[1];
    float* out = (float*)d_out;

    build_T_kernel<<<(TSZ + 255) / 256, 256, 0, stream>>>(peps);
    peps_amp_kernel<<<out_size, 512, 0, stream>>>(x, out);
}